// Round 2
// baseline (949.178 us; speedup 1.0000x reference)
//
#include <hip/hip_runtime.h>

#define DEVI __device__ __forceinline__

typedef __attribute__((ext_vector_type(8))) short short8;
typedef __attribute__((ext_vector_type(4))) float f32x4;

DEVI float bf2f(unsigned short u) {
    union { unsigned i; float f; } v; v.i = ((unsigned)u) << 16; return v.f;
}
DEVI unsigned short f2bf(float f) {
    union { float f; unsigned i; } v; v.f = f;
    unsigned i = v.i;
    unsigned r = (i + 0x7FFFu + ((i >> 16) & 1u)) >> 16;
    return (unsigned short)r;
}

// window id -> global token index for local token m (WS=4x4x4, D=32,H=64,W=64)
DEVI int dewin(int win, int m) {
    int wd = win >> 8, wh = (win >> 4) & 15, ww = win & 15;
    int d = (wd << 2) + (m >> 4);
    int h = (wh << 2) + ((m >> 2) & 3);
    int w = (ww << 2) + (m & 3);
    return (d << 12) + (h << 6) + w;   // d*4096 + h*64 + w
}

// params mirror element offsets
#define PG1   0
#define PB1   192
#define PQKVB 384
#define PRPB  960
#define PPB   3018
#define PG2   3210
#define PB2   3402
#define PF1B  3594
#define PF2B  4362
#define PTOT  4554

// ---------------- dtype sniff: 1 = float32 inputs, 0 = bf16 ----------------
__global__ void sniff_kernel(const unsigned short* __restrict__ xu, int* __restrict__ flag)
{
    if (threadIdx.x == 0 && blockIdx.x == 0) {
        int cnt = 0;
        for (int i = 0; i < 128; ++i) {
            unsigned e = (xu[i] >> 7) & 0xFF;
            if (e >= 0x68 && e <= 0x8F) ++cnt;
        }
        *flag = (cnt < 110) ? 1 : 0;
    }
}

// ---------------- convert small params to bf16 mirror ----------------
__global__ __launch_bounds__(256) void convparams_kernel(
    const void* g1, const void* b1, const void* qkvb, const void* rpb,
    const void* pb, const void* g2, const void* b2, const void* f1b,
    const void* f2b, const int* __restrict__ flag, unsigned short* __restrict__ pm)
{
    int isf = *flag;
    int idx = blockIdx.x * 256 + threadIdx.x;
    if (idx >= PTOT) return;
    const void* src; int off;
    if (idx < 192)       { src = g1;   off = idx; }
    else if (idx < 960)  { if (idx < 384) { src = b1; off = idx - 192; }
                           else           { src = qkvb; off = idx - 384; } }
    else if (idx < 3018) { src = rpb;  off = idx - 960; }
    else if (idx < 3402) { if (idx < 3210) { src = pb; off = idx - 3018; }
                           else            { src = g2; off = idx - 3210; } }
    else if (idx < 3594) { src = b2;   off = idx - 3402; }
    else if (idx < 4362) { src = f1b;  off = idx - 3594; }
    else                 { src = f2b;  off = idx - 4362; }
    unsigned short v = isf ? f2bf(((const float*)src)[off])
                           : ((const unsigned short*)src)[off];
    pm[idx] = v;
}

// ---------------- weight transpose: dst[c*R+r] = bf16(src[r*C+c]) ----------------
__global__ __launch_bounds__(256) void wtrans_kernel(
    const void* w0, const void* w1, const void* w2, const void* w3,
    unsigned short* __restrict__ t0, unsigned short* __restrict__ t1,
    unsigned short* __restrict__ t2, unsigned short* __restrict__ t3,
    const int* __restrict__ flag)
{
    int isf = *flag;
    int mat = blockIdx.y;
    const void* src; unsigned short* dst; int R, C;
    if (mat == 0)      { src = w0; dst = t0; R = 192; C = 576; }
    else if (mat == 1) { src = w1; dst = t1; R = 192; C = 192; }
    else if (mat == 2) { src = w2; dst = t2; R = 192; C = 768; }
    else               { src = w3; dst = t3; R = 768; C = 192; }
    int idx = blockIdx.x * 256 + threadIdx.x;
    if (idx < R * C) {
        int c = idx / R, r = idx - c * R;
        unsigned short v = isf ? f2bf(((const float*)src)[r * C + c])
                               : ((const unsigned short*)src)[r * C + c];
        dst[idx] = v;
    }
}

// ---------------- LN1 + QKV GEMM ----------------
// grid (3, 2048): x = part (0:q from y, 1:k from x, 2:v from x), y = window
__global__ __launch_bounds__(256) void qkv_kernel(
    const void* __restrict__ xin, const void* __restrict__ yin,
    const unsigned short* __restrict__ pm,
    const unsigned short* __restrict__ qkvT,
    unsigned short* __restrict__ q, unsigned short* __restrict__ k,
    unsigned short* __restrict__ v, const int* __restrict__ flag)
{
    __shared__ __align__(16) unsigned short A[64 * 200];
    __shared__ __align__(16) unsigned short Bt[64 * 200];
    __shared__ float GN[192], BN[192];

    int isf = *flag;
    int tid = threadIdx.x;
    int p = blockIdx.x, win = blockIdx.y;

    if (tid < 192) { GN[tid] = bf2f(pm[PG1 + tid]); BN[tid] = bf2f(pm[PB1 + tid]); }

    // load raw window rows (de-windowed gather)
    if (!isf) {
        const unsigned short* src = (p == 0) ? (const unsigned short*)yin : (const unsigned short*)xin;
        #pragma unroll
        for (int it = 0; it < 6; ++it) {
            int idx = tid + it * 256;
            int m = idx / 24, kv = idx - m * 24;
            *(uint4*)(&A[m * 200 + kv * 8]) =
                *(const uint4*)(src + (size_t)dewin(win, m) * 192 + kv * 8);
        }
    } else {
        const float* src = (p == 0) ? (const float*)yin : (const float*)xin;
        #pragma unroll
        for (int it = 0; it < 6; ++it) {
            int idx = tid + it * 256;
            int m = idx / 24, kv = idx - m * 24;
            const float* gp = src + (size_t)dewin(win, m) * 192 + kv * 8;
            unsigned short tmp[8];
            #pragma unroll
            for (int ii = 0; ii < 8; ++ii) tmp[ii] = f2bf(gp[ii]);
            *(uint4*)(&A[m * 200 + kv * 8]) = *(uint4*)tmp;
        }
    }
    __syncthreads();

    // layernorm in place (4 threads/token)
    int tok = tid >> 2, q4 = tid & 3;
    float s = 0.f, ss = 0.f;
    for (int c = q4 * 48; c < q4 * 48 + 48; ++c) {
        float vv = bf2f(A[tok * 200 + c]); s += vv; ss += vv * vv;
    }
    s += __shfl_xor(s, 1); s += __shfl_xor(s, 2);
    ss += __shfl_xor(ss, 1); ss += __shfl_xor(ss, 2);
    float mean = s * (1.f / 192.f);
    float var = ss * (1.f / 192.f) - mean * mean;
    float rstd = rsqrtf(fmaxf(var, 0.f) + 1e-5f);
    for (int c = q4 * 48; c < q4 * 48 + 48; ++c) {
        float vv = (bf2f(A[tok * 200 + c]) - mean) * rstd * GN[c] + BN[c];
        A[tok * 200 + c] = f2bf(vv);
    }
    __syncthreads();

    int wv = tid >> 6, ln = tid & 63;
    int m0 = wv * 16;
    int lrow = ln & 15, lk = (ln >> 4) * 8;
    unsigned short* outp = (p == 0) ? q : (p == 1) ? k : v;

    for (int cn = 0; cn < 3; ++cn) {
        __syncthreads();
        #pragma unroll
        for (int it = 0; it < 6; ++it) {
            int idx = tid + it * 256;
            int n = idx / 24, kv = idx - n * 24;
            *(uint4*)(&Bt[n * 200 + kv * 8]) =
                *(const uint4*)(qkvT + ((size_t)(p * 192 + cn * 64 + n)) * 192 + kv * 8);
        }
        __syncthreads();

        f32x4 acc[4] = {};
        #pragma unroll
        for (int ks = 0; ks < 6; ++ks) {
            short8 a = *(const short8*)(&A[(m0 + lrow) * 200 + ks * 32 + lk]);
            #pragma unroll
            for (int nf = 0; nf < 4; ++nf) {
                short8 b = *(const short8*)(&Bt[(nf * 16 + lrow) * 200 + ks * 32 + lk]);
                acc[nf] = __builtin_amdgcn_mfma_f32_16x16x32_bf16(a, b, acc[nf], 0, 0, 0);
            }
        }
        #pragma unroll
        for (int nf = 0; nf < 4; ++nf) {
            #pragma unroll
            for (int r = 0; r < 4; ++r) {
                int row = m0 + (ln >> 4) * 4 + r;
                int cp = cn * 64 + nf * 16 + (ln & 15);   // 0..191 within part
                float val = acc[nf][r] + bf2f(pm[PQKVB + p * 192 + cp]);
                if (p == 0) val *= 0.17677669529663687f;  // HEAD_DIM^-0.5
                int head = cp >> 5, hd = cp & 31;
                outp[(((size_t)win * 6 + head) * 64 + row) * 32 + hd] = f2bf(val);
            }
        }
    }
}

// ---------------- attention per (head, window) ----------------
__global__ __launch_bounds__(256) void attn_kernel(
    const unsigned short* __restrict__ q, const unsigned short* __restrict__ k,
    const unsigned short* __restrict__ v, const unsigned short* __restrict__ pm,
    unsigned short* __restrict__ ao)
{
    int head = blockIdx.x, win = blockIdx.y;
    __shared__ float qs[64 * 33], ks[64 * 33], vs[64 * 33];
    __shared__ float ps[64 * 66];
    int tid = threadIdx.x;
    size_t base = ((size_t)win * 6 + head) * 2048;

    {
        int m = tid >> 2, d0 = (tid & 3) * 8;
        short8 lq = *(const short8*)(q + base + (size_t)tid * 8);
        short8 lk = *(const short8*)(k + base + (size_t)tid * 8);
        short8 lv = *(const short8*)(v + base + (size_t)tid * 8);
        #pragma unroll
        for (int ii = 0; ii < 8; ++ii) {
            qs[m * 33 + d0 + ii] = bf2f((unsigned short)lq[ii]);
            ks[m * 33 + d0 + ii] = bf2f((unsigned short)lk[ii]);
            vs[m * 33 + d0 + ii] = bf2f((unsigned short)lv[ii]);
        }
    }
    __syncthreads();

    int i = tid >> 2, jg = tid & 3;
    int di = i >> 4, hi = (i >> 2) & 3, wi = i & 3;

    float qr[32];
    #pragma unroll
    for (int d = 0; d < 32; ++d) qr[d] = qs[i * 33 + d];

    float e[16];
    float mx = -1e30f;
    #pragma unroll
    for (int jj = 0; jj < 16; ++jj) {
        int j = jg * 16 + jj;
        float dot = 0.f;
        #pragma unroll
        for (int d = 0; d < 32; ++d) dot += qr[d] * ks[j * 33 + d];
        int dj = j >> 4, hj = (j >> 2) & 3, wj = j & 3;
        int bidx = ((di - dj + 3) * 7 + (hi - hj + 3)) * 7 + (wi - wj + 3);
        dot += bf2f(pm[PRPB + bidx * 6 + head]);
        e[jj] = dot;
        mx = fmaxf(mx, dot);
    }
    mx = fmaxf(mx, __shfl_xor(mx, 1));
    mx = fmaxf(mx, __shfl_xor(mx, 2));
    float sum = 0.f;
    #pragma unroll
    for (int jj = 0; jj < 16; ++jj) { e[jj] = expf(e[jj] - mx); sum += e[jj]; }
    sum += __shfl_xor(sum, 1); sum += __shfl_xor(sum, 2);
    float inv = 1.f / sum;
    #pragma unroll
    for (int jj = 0; jj < 16; ++jj) ps[i * 66 + jg * 16 + jj] = e[jj] * inv;
    __syncthreads();

    int dg = tid & 3;
    float o[8] = {0.f, 0.f, 0.f, 0.f, 0.f, 0.f, 0.f, 0.f};
    for (int j = 0; j < 64; ++j) {
        float pv = ps[i * 66 + j];
        #pragma unroll
        for (int dd = 0; dd < 8; ++dd) o[dd] += pv * vs[j * 33 + dg * 8 + dd];
    }
    short8 pack;
    #pragma unroll
    for (int dd = 0; dd < 8; ++dd) pack[dd] = (short)f2bf(o[dd]);
    size_t dst = ((size_t)win * 64 + i) * 192 + head * 32 + dg * 8;
    *(short8*)(ao + dst) = pack;
}

// ---------------- proj + residual -> x1 (window order) ----------------
__global__ __launch_bounds__(256) void proj_kernel(
    const unsigned short* __restrict__ ao, const unsigned short* __restrict__ pT,
    const unsigned short* __restrict__ pm, const void* __restrict__ xin,
    unsigned short* __restrict__ x1, const int* __restrict__ flag)
{
    __shared__ __align__(16) unsigned short A[64 * 200];
    __shared__ __align__(16) unsigned short Bt[64 * 200];
    int isf = *flag;
    int tid = threadIdx.x, win = blockIdx.x;

    #pragma unroll
    for (int it = 0; it < 6; ++it) {
        int idx = tid + it * 256;
        int m = idx / 24, kv = idx - m * 24;
        *(uint4*)(&A[m * 200 + kv * 8]) =
            *(const uint4*)(ao + (size_t)win * 12288 + m * 192 + kv * 8);
    }

    int wv = tid >> 6, ln = tid & 63;
    int m0 = wv * 16, lrow = ln & 15, lk = (ln >> 4) * 8;

    for (int cn = 0; cn < 3; ++cn) {
        __syncthreads();
        #pragma unroll
        for (int it = 0; it < 6; ++it) {
            int idx = tid + it * 256;
            int n = idx / 24, kv = idx - n * 24;
            *(uint4*)(&Bt[n * 200 + kv * 8]) =
                *(const uint4*)(pT + ((size_t)(cn * 64 + n)) * 192 + kv * 8);
        }
        __syncthreads();

        f32x4 acc[4] = {};
        #pragma unroll
        for (int ks = 0; ks < 6; ++ks) {
            short8 a = *(const short8*)(&A[(m0 + lrow) * 200 + ks * 32 + lk]);
            #pragma unroll
            for (int nf = 0; nf < 4; ++nf) {
                short8 b = *(const short8*)(&Bt[(nf * 16 + lrow) * 200 + ks * 32 + lk]);
                acc[nf] = __builtin_amdgcn_mfma_f32_16x16x32_bf16(a, b, acc[nf], 0, 0, 0);
            }
        }
        #pragma unroll
        for (int nf = 0; nf < 4; ++nf) {
            #pragma unroll
            for (int r = 0; r < 4; ++r) {
                int row = m0 + (ln >> 4) * 4 + r;
                int c = cn * 64 + nf * 16 + (ln & 15);
                size_t gidx = (size_t)dewin(win, row) * 192 + c;
                float res = isf ? ((const float*)xin)[gidx]
                                : bf2f(((const unsigned short*)xin)[gidx]);
                float val = acc[nf][r] + bf2f(pm[PPB + c]) + res;
                x1[((size_t)win * 64 + row) * 192 + c] = f2bf(val);
            }
        }
    }
}

// ---------------- LN2 + fc1 + gelu -> h ----------------
// grid (4, 2048): x = 192-col group, y = window
__global__ __launch_bounds__(256) void m1_kernel(
    const unsigned short* __restrict__ x1, const unsigned short* __restrict__ pm,
    const unsigned short* __restrict__ f1T, unsigned short* __restrict__ h)
{
    __shared__ __align__(16) unsigned short A[64 * 200];
    __shared__ __align__(16) unsigned short Bt[64 * 200];
    __shared__ float GN[192], BN[192];
    int tid = threadIdx.x;
    int p = blockIdx.x, win = blockIdx.y;

    if (tid < 192) { GN[tid] = bf2f(pm[PG2 + tid]); BN[tid] = bf2f(pm[PB2 + tid]); }

    #pragma unroll
    for (int it = 0; it < 6; ++it) {
        int idx = tid + it * 256;
        int m = idx / 24, kv = idx - m * 24;
        *(uint4*)(&A[m * 200 + kv * 8]) =
            *(const uint4*)(x1 + (size_t)win * 12288 + m * 192 + kv * 8);
    }
    __syncthreads();

    int tok = tid >> 2, q4 = tid & 3;
    float s = 0.f, ss = 0.f;
    for (int c = q4 * 48; c < q4 * 48 + 48; ++c) {
        float vv = bf2f(A[tok * 200 + c]); s += vv; ss += vv * vv;
    }
    s += __shfl_xor(s, 1); s += __shfl_xor(s, 2);
    ss += __shfl_xor(ss, 1); ss += __shfl_xor(ss, 2);
    float mean = s * (1.f / 192.f);
    float var = ss * (1.f / 192.f) - mean * mean;
    float rstd = rsqrtf(fmaxf(var, 0.f) + 1e-5f);
    for (int c = q4 * 48; c < q4 * 48 + 48; ++c) {
        float vv = (bf2f(A[tok * 200 + c]) - mean) * rstd * GN[c] + BN[c];
        A[tok * 200 + c] = f2bf(vv);
    }
    __syncthreads();

    int wv = tid >> 6, ln = tid & 63;
    int m0 = wv * 16, lrow = ln & 15, lk = (ln >> 4) * 8;

    for (int cn = 0; cn < 3; ++cn) {
        __syncthreads();
        #pragma unroll
        for (int it = 0; it < 6; ++it) {
            int idx = tid + it * 256;
            int n = idx / 24, kv = idx - n * 24;
            *(uint4*)(&Bt[n * 200 + kv * 8]) =
                *(const uint4*)(f1T + ((size_t)(p * 192 + cn * 64 + n)) * 192 + kv * 8);
        }
        __syncthreads();

        f32x4 acc[4] = {};
        #pragma unroll
        for (int ks = 0; ks < 6; ++ks) {
            short8 a = *(const short8*)(&A[(m0 + lrow) * 200 + ks * 32 + lk]);
            #pragma unroll
            for (int nf = 0; nf < 4; ++nf) {
                short8 b = *(const short8*)(&Bt[(nf * 16 + lrow) * 200 + ks * 32 + lk]);
                acc[nf] = __builtin_amdgcn_mfma_f32_16x16x32_bf16(a, b, acc[nf], 0, 0, 0);
            }
        }
        #pragma unroll
        for (int nf = 0; nf < 4; ++nf) {
            #pragma unroll
            for (int r = 0; r < 4; ++r) {
                int row = m0 + (ln >> 4) * 4 + r;
                int c = p * 192 + cn * 64 + nf * 16 + (ln & 15);   // 0..767
                float val = acc[nf][r] + bf2f(pm[PF1B + c]);
                val = 0.5f * val * (1.f + erff(val * 0.70710678118654752f));
                h[((size_t)win * 64 + row) * 768 + c] = f2bf(val);
            }
        }
    }
}

// ---------------- fc2 + residual + window_reverse -> out ----------------
__global__ __launch_bounds__(256) void m2_kernel(
    const unsigned short* __restrict__ h, const unsigned short* __restrict__ f2T,
    const unsigned short* __restrict__ pm, const unsigned short* __restrict__ x1,
    void* __restrict__ out, const int* __restrict__ flag)
{
    __shared__ __align__(16) unsigned short A[64 * 264];
    __shared__ __align__(16) unsigned short Bt[64 * 264];
    int isf = *flag;
    int tid = threadIdx.x, win = blockIdx.x;
    int wv = tid >> 6, ln = tid & 63;
    int m0 = wv * 16, lrow = ln & 15, lk = (ln >> 4) * 8;

    f32x4 acc[12] = {};

    for (int kc = 0; kc < 3; ++kc) {
        __syncthreads();
        #pragma unroll
        for (int it = 0; it < 8; ++it) {
            int idx = tid + it * 256;
            int m = idx >> 5, kv = idx & 31;
            *(uint4*)(&A[m * 264 + kv * 8]) =
                *(const uint4*)(h + ((size_t)win * 64 + m) * 768 + kc * 256 + kv * 8);
        }
        for (int nsub = 0; nsub < 3; ++nsub) {
            __syncthreads();
            #pragma unroll
            for (int it = 0; it < 8; ++it) {
                int idx = tid + it * 256;
                int n = idx >> 5, kv = idx & 31;
                *(uint4*)(&Bt[n * 264 + kv * 8]) =
                    *(const uint4*)(f2T + ((size_t)(nsub * 64 + n)) * 768 + kc * 256 + kv * 8);
            }
            __syncthreads();
            #pragma unroll
            for (int ks = 0; ks < 8; ++ks) {
                short8 a = *(const short8*)(&A[(m0 + lrow) * 264 + ks * 32 + lk]);
                #pragma unroll
                for (int nf = 0; nf < 4; ++nf) {
                    short8 b = *(const short8*)(&Bt[(nf * 16 + lrow) * 264 + ks * 32 + lk]);
                    acc[nsub * 4 + nf] =
                        __builtin_amdgcn_mfma_f32_16x16x32_bf16(a, b, acc[nsub * 4 + nf], 0, 0, 0);
                }
            }
        }
    }

    #pragma unroll
    for (int f = 0; f < 12; ++f) {
        #pragma unroll
        for (int r = 0; r < 4; ++r) {
            int row = m0 + (ln >> 4) * 4 + r;
            int col = f * 16 + (ln & 15);
            int g = dewin(win, row);
            float val = acc[f][r] + bf2f(pm[PF2B + col])
                      + bf2f(x1[((size_t)win * 64 + row) * 192 + col]);
            // NaN sentinel: if any non-finite reached here, flag it visibly
            if (!(val == val) || fabsf(val) > 1e30f) val = 9999.0f;
            if (isf) ((float*)out)[(size_t)g * 192 + col] = val;
            else     ((unsigned short*)out)[(size_t)g * 192 + col] = f2bf(val);
        }
    }
}

// ---------------- launch ----------------
extern "C" void kernel_launch(void* const* d_in, const int* in_sizes, int n_in,
                              void* d_out, int out_size, void* d_ws, size_t ws_size,
                              hipStream_t stream)
{
    const void* x    = d_in[0];
    const void* y    = d_in[1];
    const void* g1   = d_in[3];
    const void* b1   = d_in[4];
    const void* qkvw = d_in[5];
    const void* qkvb = d_in[6];
    const void* rpb  = d_in[7];
    const void* pw   = d_in[8];
    const void* pb   = d_in[9];
    const void* g2   = d_in[10];
    const void* b2   = d_in[11];
    const void* f1w  = d_in[12];
    const void* f1b  = d_in[13];
    const void* f2w  = d_in[14];
    const void* f2b  = d_in[15];

    char* ws = (char*)d_ws;
    const size_t OFF_Q    = 0;
    const size_t OFF_K    = 50331648;
    const size_t OFF_V    = 100663296;
    const size_t OFF_AO   = 150994944;
    const size_t OFF_X1   = 201326592;
    const size_t OFF_H    = 0;            // aliases q/k/v/ao (dead by then)
    const size_t OFF_PM   = 251658240;
    const size_t OFF_QKVT = 251674624;
    const size_t OFF_PT   = 251895808;
    const size_t OFF_F1T  = 251969536;
    const size_t OFF_F2T  = 252264448;
    const size_t OFF_FLAG = 252559360;
    const size_t WS_NEED  = 252559376;
    if (ws_size < WS_NEED) return;

    unsigned short* q    = (unsigned short*)(ws + OFF_Q);
    unsigned short* k    = (unsigned short*)(ws + OFF_K);
    unsigned short* v    = (unsigned short*)(ws + OFF_V);
    unsigned short* ao   = (unsigned short*)(ws + OFF_AO);
    unsigned short* x1   = (unsigned short*)(ws + OFF_X1);
    unsigned short* hbuf = (unsigned short*)(ws + OFF_H);
    unsigned short* pmir = (unsigned short*)(ws + OFF_PM);
    unsigned short* qkvT = (unsigned short*)(ws + OFF_QKVT);
    unsigned short* pT   = (unsigned short*)(ws + OFF_PT);
    unsigned short* f1T  = (unsigned short*)(ws + OFF_F1T);
    unsigned short* f2T  = (unsigned short*)(ws + OFF_F2T);
    int* flag            = (int*)(ws + OFF_FLAG);

    sniff_kernel<<<dim3(1), 64, 0, stream>>>((const unsigned short*)x, flag);
    convparams_kernel<<<dim3(18), 256, 0, stream>>>(g1, b1, qkvb, rpb, pb, g2, b2, f1b, f2b, flag, pmir);
    wtrans_kernel<<<dim3(576, 4), 256, 0, stream>>>(qkvw, pw, f1w, f2w, qkvT, pT, f1T, f2T, flag);
    qkv_kernel<<<dim3(3, 2048), 256, 0, stream>>>(x, y, pmir, qkvT, q, k, v, flag);
    attn_kernel<<<dim3(6, 2048), 256, 0, stream>>>(q, k, v, pmir, ao);
    proj_kernel<<<dim3(2048), 256, 0, stream>>>(ao, pT, pmir, x, x1, flag);
    m1_kernel<<<dim3(4, 2048), 256, 0, stream>>>(x1, pmir, f1T, hbuf);
    m2_kernel<<<dim3(2048), 256, 0, stream>>>(hbuf, f2T, pmir, x1, d_out, flag);
}

// Round 3
// 742.926 us; speedup vs baseline: 1.2776x; 1.2776x over previous
//
#include <hip/hip_runtime.h>

#define DEVI __device__ __forceinline__

typedef __attribute__((ext_vector_type(8))) short short8;
typedef __attribute__((ext_vector_type(4))) float f32x4;

DEVI float bf2f(unsigned short u) {
    union { unsigned i; float f; } v; v.i = ((unsigned)u) << 16; return v.f;
}
DEVI unsigned short f2bf(float f) {
    union { float f; unsigned i; } v; v.f = f;
    unsigned i = v.i;
    unsigned r = (i + 0x7FFFu + ((i >> 16) & 1u)) >> 16;
    return (unsigned short)r;
}

// window id -> global token index for local token m (WS=4x4x4, D=32,H=64,W=64)
DEVI int dewin(int win, int m) {
    int wd = win >> 8, wh = (win >> 4) & 15, ww = win & 15;
    int d = (wd << 2) + (m >> 4);
    int h = (wh << 2) + ((m >> 2) & 3);
    int w = (ww << 2) + (m & 3);
    return (d << 12) + (h << 6) + w;   // d*4096 + h*64 + w
}

// params mirror element offsets
#define PG1   0
#define PB1   192
#define PQKVB 384
#define PRPB  960
#define PPB   3018
#define PG2   3210
#define PB2   3402
#define PF1B  3594
#define PF2B  4362
#define PTOT  4554

// ---------------- dtype sniff: 1 = float32 inputs, 0 = bf16 ----------------
__global__ void sniff_kernel(const unsigned short* __restrict__ xu, int* __restrict__ flag)
{
    if (threadIdx.x == 0 && blockIdx.x == 0) {
        int cnt = 0;
        for (int i = 0; i < 128; ++i) {
            unsigned e = (xu[i] >> 7) & 0xFF;
            if (e >= 0x68 && e <= 0x8F) ++cnt;
        }
        *flag = (cnt < 110) ? 1 : 0;
    }
}

// ---------------- convert small params to bf16 mirror ----------------
__global__ __launch_bounds__(256) void convparams_kernel(
    const void* g1, const void* b1, const void* qkvb, const void* rpb,
    const void* pb, const void* g2, const void* b2, const void* f1b,
    const void* f2b, const int* __restrict__ flag, unsigned short* __restrict__ pm)
{
    int isf = *flag;
    int idx = blockIdx.x * 256 + threadIdx.x;
    if (idx >= PTOT) return;
    const void* src; int off;
    if (idx < 192)       { src = g1;   off = idx; }
    else if (idx < 960)  { if (idx < 384) { src = b1; off = idx - 192; }
                           else           { src = qkvb; off = idx - 384; } }
    else if (idx < 3018) { src = rpb;  off = idx - 960; }
    else if (idx < 3402) { if (idx < 3210) { src = pb; off = idx - 3018; }
                           else            { src = g2; off = idx - 3210; } }
    else if (idx < 3594) { src = b2;   off = idx - 3402; }
    else if (idx < 4362) { src = f1b;  off = idx - 3594; }
    else                 { src = f2b;  off = idx - 4362; }
    unsigned short v = isf ? f2bf(((const float*)src)[off])
                           : ((const unsigned short*)src)[off];
    pm[idx] = v;
}

// ---------------- bias table: biasb[head][i][j] = rpb[REL_IDX[i][j]][head] ----------------
__global__ __launch_bounds__(256) void biasprep_kernel(
    const unsigned short* __restrict__ pm, unsigned short* __restrict__ biasb)
{
    int idx = blockIdx.x * 256 + threadIdx.x;   // 6 * 4096 = 24576
    if (idx >= 24576) return;
    int head = idx >> 12, ij = idx & 4095;
    int i = ij >> 6, j = ij & 63;
    int di = i >> 4, hi = (i >> 2) & 3, wi = i & 3;
    int dj = j >> 4, hj = (j >> 2) & 3, wj = j & 3;
    int bidx = ((di - dj + 3) * 7 + (hi - hj + 3)) * 7 + (wi - wj + 3);
    biasb[idx] = pm[PRPB + bidx * 6 + head];
}

// ---------------- weight transpose: dst[c*R+r] = bf16(src[r*C+c]) ----------------
__global__ __launch_bounds__(256) void wtrans_kernel(
    const void* w0, const void* w1, const void* w2, const void* w3,
    unsigned short* __restrict__ t0, unsigned short* __restrict__ t1,
    unsigned short* __restrict__ t2, unsigned short* __restrict__ t3,
    const int* __restrict__ flag)
{
    int isf = *flag;
    int mat = blockIdx.y;
    const void* src; unsigned short* dst; int R, C;
    if (mat == 0)      { src = w0; dst = t0; R = 192; C = 576; }
    else if (mat == 1) { src = w1; dst = t1; R = 192; C = 192; }
    else if (mat == 2) { src = w2; dst = t2; R = 192; C = 768; }
    else               { src = w3; dst = t3; R = 768; C = 192; }
    int idx = blockIdx.x * 256 + threadIdx.x;
    if (idx < R * C) {
        int c = idx / R, r = idx - c * R;
        unsigned short v = isf ? f2bf(((const float*)src)[r * C + c])
                               : ((const unsigned short*)src)[r * C + c];
        dst[idx] = v;
    }
}

// ---------------- LN1 + QKV GEMM ----------------
// grid (3, 2048): x = part (0:q from y, 1:k from x, 2:v from x), y = window
__global__ __launch_bounds__(256) void qkv_kernel(
    const void* __restrict__ xin, const void* __restrict__ yin,
    const unsigned short* __restrict__ pm,
    const unsigned short* __restrict__ qkvT,
    unsigned short* __restrict__ q, unsigned short* __restrict__ k,
    unsigned short* __restrict__ v, const int* __restrict__ flag)
{
    __shared__ __align__(16) unsigned short A[64 * 200];
    __shared__ __align__(16) unsigned short Bt[64 * 200];
    __shared__ float GN[192], BN[192];

    int isf = *flag;
    int tid = threadIdx.x;
    int p = blockIdx.x, win = blockIdx.y;

    if (tid < 192) { GN[tid] = bf2f(pm[PG1 + tid]); BN[tid] = bf2f(pm[PB1 + tid]); }

    // load raw window rows (de-windowed gather)
    if (!isf) {
        const unsigned short* src = (p == 0) ? (const unsigned short*)yin : (const unsigned short*)xin;
        #pragma unroll
        for (int it = 0; it < 6; ++it) {
            int idx = tid + it * 256;
            int m = idx / 24, kv = idx - m * 24;
            *(uint4*)(&A[m * 200 + kv * 8]) =
                *(const uint4*)(src + (size_t)dewin(win, m) * 192 + kv * 8);
        }
    } else {
        const float* src = (p == 0) ? (const float*)yin : (const float*)xin;
        #pragma unroll
        for (int it = 0; it < 6; ++it) {
            int idx = tid + it * 256;
            int m = idx / 24, kv = idx - m * 24;
            const float* gp = src + (size_t)dewin(win, m) * 192 + kv * 8;
            unsigned short tmp[8];
            #pragma unroll
            for (int ii = 0; ii < 8; ++ii) tmp[ii] = f2bf(gp[ii]);
            *(uint4*)(&A[m * 200 + kv * 8]) = *(uint4*)tmp;
        }
    }
    __syncthreads();

    // layernorm in place (4 threads/token)
    int tok = tid >> 2, q4 = tid & 3;
    float s = 0.f, ss = 0.f;
    for (int c = q4 * 48; c < q4 * 48 + 48; ++c) {
        float vv = bf2f(A[tok * 200 + c]); s += vv; ss += vv * vv;
    }
    s += __shfl_xor(s, 1); s += __shfl_xor(s, 2);
    ss += __shfl_xor(ss, 1); ss += __shfl_xor(ss, 2);
    float mean = s * (1.f / 192.f);
    float var = ss * (1.f / 192.f) - mean * mean;
    float rstd = rsqrtf(fmaxf(var, 0.f) + 1e-5f);
    for (int c = q4 * 48; c < q4 * 48 + 48; ++c) {
        float vv = (bf2f(A[tok * 200 + c]) - mean) * rstd * GN[c] + BN[c];
        A[tok * 200 + c] = f2bf(vv);
    }
    __syncthreads();

    int wv = tid >> 6, ln = tid & 63;
    int m0 = wv * 16;
    int lrow = ln & 15, lk = (ln >> 4) * 8;
    unsigned short* outp = (p == 0) ? q : (p == 1) ? k : v;

    for (int cn = 0; cn < 3; ++cn) {
        __syncthreads();
        #pragma unroll
        for (int it = 0; it < 6; ++it) {
            int idx = tid + it * 256;
            int n = idx / 24, kv = idx - n * 24;
            *(uint4*)(&Bt[n * 200 + kv * 8]) =
                *(const uint4*)(qkvT + ((size_t)(p * 192 + cn * 64 + n)) * 192 + kv * 8);
        }
        __syncthreads();

        f32x4 acc[4] = {};
        #pragma unroll
        for (int ks = 0; ks < 6; ++ks) {
            short8 a = *(const short8*)(&A[(m0 + lrow) * 200 + ks * 32 + lk]);
            #pragma unroll
            for (int nf = 0; nf < 4; ++nf) {
                short8 b = *(const short8*)(&Bt[(nf * 16 + lrow) * 200 + ks * 32 + lk]);
                acc[nf] = __builtin_amdgcn_mfma_f32_16x16x32_bf16(a, b, acc[nf], 0, 0, 0);
            }
        }
        #pragma unroll
        for (int nf = 0; nf < 4; ++nf) {
            #pragma unroll
            for (int r = 0; r < 4; ++r) {
                int row = m0 + (ln >> 4) * 4 + r;
                int cp = cn * 64 + nf * 16 + (ln & 15);   // 0..191 within part
                float val = acc[nf][r] + bf2f(pm[PQKVB + p * 192 + cp]);
                if (p == 0) val *= 0.17677669529663687f;  // HEAD_DIM^-0.5
                int head = cp >> 5, hd = cp & 31;
                outp[(((size_t)win * 6 + head) * 64 + row) * 32 + hd] = f2bf(val);
            }
        }
    }
}

// ---------------- MFMA attention per (head, window) ----------------
// 4 waves; wave w owns rows [w*16, w*16+16) of the 64x64 score tile.
__global__ __launch_bounds__(256) void attn_kernel(
    const unsigned short* __restrict__ q, const unsigned short* __restrict__ k,
    const unsigned short* __restrict__ v, const unsigned short* __restrict__ biasb,
    unsigned short* __restrict__ ao)
{
    // strides: 40 elems = 80 B (16B-aligned, bank period 8 -> free 2-way)
    //          72 elems = 144 B (16B-aligned)
    __shared__ __align__(16) unsigned short Qs[64 * 40];
    __shared__ __align__(16) unsigned short Ks[64 * 40];
    __shared__ __align__(16) unsigned short Vs[64 * 40];
    __shared__ __align__(16) unsigned short Vt[32 * 72];
    __shared__ __align__(16) unsigned short Ps[64 * 72];

    int head = blockIdx.x, win = blockIdx.y;
    int tid = threadIdx.x;
    size_t base = ((size_t)win * 6 + head) * 2048;

    {   // load q,k,v rows: 8 bf16 per thread each
        int tok = tid >> 2, d0 = (tid & 3) * 8;
        *(uint4*)(&Qs[tok * 40 + d0]) = *(const uint4*)(q + base + tok * 32 + d0);
        *(uint4*)(&Ks[tok * 40 + d0]) = *(const uint4*)(k + base + tok * 32 + d0);
        *(uint4*)(&Vs[tok * 40 + d0]) = *(const uint4*)(v + base + tok * 32 + d0);
    }
    __syncthreads();

    {   // transpose V -> Vt[d][j]
        int d = tid & 31, j0 = (tid >> 5) * 8;
        unsigned short tmp[8];
        #pragma unroll
        for (int ii = 0; ii < 8; ++ii) tmp[ii] = Vs[(j0 + ii) * 40 + d];
        *(uint4*)(&Vt[d * 72 + j0]) = *(uint4*)tmp;
    }

    int w = tid >> 6, ln = tid & 63;
    int lrow = ln & 15, lk8 = (ln >> 4) * 8;
    int rbase = w * 16 + (ln >> 4) * 4;           // global row of reg r = rbase + r

    // S = Q K^T for this wave's 16-row strip (K-dim = 32 = one MFMA)
    short8 aq = *(const short8*)(&Qs[(w * 16 + lrow) * 40 + lk8]);
    f32x4 s[4];
    #pragma unroll
    for (int nt = 0; nt < 4; ++nt) {
        short8 bk = *(const short8*)(&Ks[(nt * 16 + lrow) * 40 + lk8]);
        f32x4 z = {};
        s[nt] = __builtin_amdgcn_mfma_f32_16x16x32_bf16(aq, bk, z, 0, 0, 0);
    }

    // bias + row-softmax (rows live in regs: row = rbase + r, col = nt*16 + lrow)
    const unsigned short* bh = biasb + head * 4096;
    float mx[4] = {-1e30f, -1e30f, -1e30f, -1e30f};
    #pragma unroll
    for (int nt = 0; nt < 4; ++nt)
        #pragma unroll
        for (int r = 0; r < 4; ++r) {
            float val = s[nt][r] + bf2f(bh[(rbase + r) * 64 + nt * 16 + lrow]);
            s[nt][r] = val;
            mx[r] = fmaxf(mx[r], val);
        }
    #pragma unroll
    for (int r = 0; r < 4; ++r) {
        mx[r] = fmaxf(mx[r], __shfl_xor(mx[r], 1));
        mx[r] = fmaxf(mx[r], __shfl_xor(mx[r], 2));
        mx[r] = fmaxf(mx[r], __shfl_xor(mx[r], 4));
        mx[r] = fmaxf(mx[r], __shfl_xor(mx[r], 8));
    }
    float sum[4] = {0.f, 0.f, 0.f, 0.f};
    #pragma unroll
    for (int nt = 0; nt < 4; ++nt)
        #pragma unroll
        for (int r = 0; r < 4; ++r) {
            float e = __expf(s[nt][r] - mx[r]);
            s[nt][r] = e;
            sum[r] += e;
        }
    #pragma unroll
    for (int r = 0; r < 4; ++r) {
        sum[r] += __shfl_xor(sum[r], 1);
        sum[r] += __shfl_xor(sum[r], 2);
        sum[r] += __shfl_xor(sum[r], 4);
        sum[r] += __shfl_xor(sum[r], 8);
        sum[r] = 1.f / sum[r];
    }
    #pragma unroll
    for (int nt = 0; nt < 4; ++nt)
        #pragma unroll
        for (int r = 0; r < 4; ++r)
            Ps[(rbase + r) * 72 + nt * 16 + lrow] = f2bf(s[nt][r] * sum[r]);

    __syncthreads();   // Vt (cross-wave) + Ps ready

    // O = P V  (K-dim = 64 -> 2 k-chunks)
    f32x4 o[2] = {};
    #pragma unroll
    for (int kk = 0; kk < 2; ++kk) {
        short8 ap = *(const short8*)(&Ps[(w * 16 + lrow) * 72 + kk * 32 + lk8]);
        #pragma unroll
        for (int dt = 0; dt < 2; ++dt) {
            short8 bv = *(const short8*)(&Vt[(dt * 16 + lrow) * 72 + kk * 32 + lk8]);
            o[dt] = __builtin_amdgcn_mfma_f32_16x16x32_bf16(ap, bv, o[dt], 0, 0, 0);
        }
    }

    #pragma unroll
    for (int dt = 0; dt < 2; ++dt)
        #pragma unroll
        for (int r = 0; r < 4; ++r) {
            int row = rbase + r;
            int d = dt * 16 + lrow;
            ao[((size_t)win * 64 + row) * 192 + head * 32 + d] = f2bf(o[dt][r]);
        }
}

// ---------------- proj + residual -> x1 (window order) ----------------
__global__ __launch_bounds__(256) void proj_kernel(
    const unsigned short* __restrict__ ao, const unsigned short* __restrict__ pT,
    const unsigned short* __restrict__ pm, const void* __restrict__ xin,
    unsigned short* __restrict__ x1, const int* __restrict__ flag)
{
    __shared__ __align__(16) unsigned short A[64 * 200];
    __shared__ __align__(16) unsigned short Bt[64 * 200];
    int isf = *flag;
    int tid = threadIdx.x, win = blockIdx.x;

    #pragma unroll
    for (int it = 0; it < 6; ++it) {
        int idx = tid + it * 256;
        int m = idx / 24, kv = idx - m * 24;
        *(uint4*)(&A[m * 200 + kv * 8]) =
            *(const uint4*)(ao + (size_t)win * 12288 + m * 192 + kv * 8);
    }

    int wv = tid >> 6, ln = tid & 63;
    int m0 = wv * 16, lrow = ln & 15, lk = (ln >> 4) * 8;

    for (int cn = 0; cn < 3; ++cn) {
        __syncthreads();
        #pragma unroll
        for (int it = 0; it < 6; ++it) {
            int idx = tid + it * 256;
            int n = idx / 24, kv = idx - n * 24;
            *(uint4*)(&Bt[n * 200 + kv * 8]) =
                *(const uint4*)(pT + ((size_t)(cn * 64 + n)) * 192 + kv * 8);
        }
        __syncthreads();

        f32x4 acc[4] = {};
        #pragma unroll
        for (int ks = 0; ks < 6; ++ks) {
            short8 a = *(const short8*)(&A[(m0 + lrow) * 200 + ks * 32 + lk]);
            #pragma unroll
            for (int nf = 0; nf < 4; ++nf) {
                short8 b = *(const short8*)(&Bt[(nf * 16 + lrow) * 200 + ks * 32 + lk]);
                acc[nf] = __builtin_amdgcn_mfma_f32_16x16x32_bf16(a, b, acc[nf], 0, 0, 0);
            }
        }
        #pragma unroll
        for (int nf = 0; nf < 4; ++nf) {
            #pragma unroll
            for (int r = 0; r < 4; ++r) {
                int row = m0 + (ln >> 4) * 4 + r;
                int c = cn * 64 + nf * 16 + (ln & 15);
                size_t gidx = (size_t)dewin(win, row) * 192 + c;
                float res = isf ? ((const float*)xin)[gidx]
                                : bf2f(((const unsigned short*)xin)[gidx]);
                float val = acc[nf][r] + bf2f(pm[PPB + c]) + res;
                x1[((size_t)win * 64 + row) * 192 + c] = f2bf(val);
            }
        }
    }
}

// ---------------- LN2 + fc1 + gelu -> h ----------------
// grid (4, 2048): x = 192-col group, y = window
__global__ __launch_bounds__(256) void m1_kernel(
    const unsigned short* __restrict__ x1, const unsigned short* __restrict__ pm,
    const unsigned short* __restrict__ f1T, unsigned short* __restrict__ h)
{
    __shared__ __align__(16) unsigned short A[64 * 200];
    __shared__ __align__(16) unsigned short Bt[64 * 200];
    __shared__ float GN[192], BN[192];
    int tid = threadIdx.x;
    int p = blockIdx.x, win = blockIdx.y;

    if (tid < 192) { GN[tid] = bf2f(pm[PG2 + tid]); BN[tid] = bf2f(pm[PB2 + tid]); }

    #pragma unroll
    for (int it = 0; it < 6; ++it) {
        int idx = tid + it * 256;
        int m = idx / 24, kv = idx - m * 24;
        *(uint4*)(&A[m * 200 + kv * 8]) =
            *(const uint4*)(x1 + (size_t)win * 12288 + m * 192 + kv * 8);
    }
    __syncthreads();

    int tok = tid >> 2, q4 = tid & 3;
    float s = 0.f, ss = 0.f;
    for (int c = q4 * 48; c < q4 * 48 + 48; ++c) {
        float vv = bf2f(A[tok * 200 + c]); s += vv; ss += vv * vv;
    }
    s += __shfl_xor(s, 1); s += __shfl_xor(s, 2);
    ss += __shfl_xor(ss, 1); ss += __shfl_xor(ss, 2);
    float mean = s * (1.f / 192.f);
    float var = ss * (1.f / 192.f) - mean * mean;
    float rstd = rsqrtf(fmaxf(var, 0.f) + 1e-5f);
    for (int c = q4 * 48; c < q4 * 48 + 48; ++c) {
        float vv = (bf2f(A[tok * 200 + c]) - mean) * rstd * GN[c] + BN[c];
        A[tok * 200 + c] = f2bf(vv);
    }
    __syncthreads();

    int wv = tid >> 6, ln = tid & 63;
    int m0 = wv * 16, lrow = ln & 15, lk = (ln >> 4) * 8;

    for (int cn = 0; cn < 3; ++cn) {
        __syncthreads();
        #pragma unroll
        for (int it = 0; it < 6; ++it) {
            int idx = tid + it * 256;
            int n = idx / 24, kv = idx - n * 24;
            *(uint4*)(&Bt[n * 200 + kv * 8]) =
                *(const uint4*)(f1T + ((size_t)(p * 192 + cn * 64 + n)) * 192 + kv * 8);
        }
        __syncthreads();

        f32x4 acc[4] = {};
        #pragma unroll
        for (int ks = 0; ks < 6; ++ks) {
            short8 a = *(const short8*)(&A[(m0 + lrow) * 200 + ks * 32 + lk]);
            #pragma unroll
            for (int nf = 0; nf < 4; ++nf) {
                short8 b = *(const short8*)(&Bt[(nf * 16 + lrow) * 200 + ks * 32 + lk]);
                acc[nf] = __builtin_amdgcn_mfma_f32_16x16x32_bf16(a, b, acc[nf], 0, 0, 0);
            }
        }
        #pragma unroll
        for (int nf = 0; nf < 4; ++nf) {
            #pragma unroll
            for (int r = 0; r < 4; ++r) {
                int row = m0 + (ln >> 4) * 4 + r;
                int c = p * 192 + cn * 64 + nf * 16 + (ln & 15);   // 0..767
                float val = acc[nf][r] + bf2f(pm[PF1B + c]);
                val = 0.5f * val * (1.f + erff(val * 0.70710678118654752f));
                h[((size_t)win * 64 + row) * 768 + c] = f2bf(val);
            }
        }
    }
}

// ---------------- fc2 + residual + window_reverse -> out ----------------
__global__ __launch_bounds__(256) void m2_kernel(
    const unsigned short* __restrict__ h, const unsigned short* __restrict__ f2T,
    const unsigned short* __restrict__ pm, const unsigned short* __restrict__ x1,
    void* __restrict__ out, const int* __restrict__ flag)
{
    __shared__ __align__(16) unsigned short A[64 * 264];
    __shared__ __align__(16) unsigned short Bt[64 * 264];
    int isf = *flag;
    int tid = threadIdx.x, win = blockIdx.x;
    int wv = tid >> 6, ln = tid & 63;
    int m0 = wv * 16, lrow = ln & 15, lk = (ln >> 4) * 8;

    f32x4 acc[12] = {};

    for (int kc = 0; kc < 3; ++kc) {
        __syncthreads();
        #pragma unroll
        for (int it = 0; it < 8; ++it) {
            int idx = tid + it * 256;
            int m = idx >> 5, kv = idx & 31;
            *(uint4*)(&A[m * 264 + kv * 8]) =
                *(const uint4*)(h + ((size_t)win * 64 + m) * 768 + kc * 256 + kv * 8);
        }
        for (int nsub = 0; nsub < 3; ++nsub) {
            __syncthreads();
            #pragma unroll
            for (int it = 0; it < 8; ++it) {
                int idx = tid + it * 256;
                int n = idx >> 5, kv = idx & 31;
                *(uint4*)(&Bt[n * 264 + kv * 8]) =
                    *(const uint4*)(f2T + ((size_t)(nsub * 64 + n)) * 768 + kc * 256 + kv * 8);
            }
            __syncthreads();
            #pragma unroll
            for (int ks = 0; ks < 8; ++ks) {
                short8 a = *(const short8*)(&A[(m0 + lrow) * 264 + ks * 32 + lk]);
                #pragma unroll
                for (int nf = 0; nf < 4; ++nf) {
                    short8 b = *(const short8*)(&Bt[(nf * 16 + lrow) * 264 + ks * 32 + lk]);
                    acc[nsub * 4 + nf] =
                        __builtin_amdgcn_mfma_f32_16x16x32_bf16(a, b, acc[nsub * 4 + nf], 0, 0, 0);
                }
            }
        }
    }

    #pragma unroll
    for (int f = 0; f < 12; ++f) {
        #pragma unroll
        for (int r = 0; r < 4; ++r) {
            int row = m0 + (ln >> 4) * 4 + r;
            int col = f * 16 + (ln & 15);
            int g = dewin(win, row);
            float val = acc[f][r] + bf2f(pm[PF2B + col])
                      + bf2f(x1[((size_t)win * 64 + row) * 192 + col]);
            if (isf) ((float*)out)[(size_t)g * 192 + col] = val;
            else     ((unsigned short*)out)[(size_t)g * 192 + col] = f2bf(val);
        }
    }
}

// ---------------- launch ----------------
extern "C" void kernel_launch(void* const* d_in, const int* in_sizes, int n_in,
                              void* d_out, int out_size, void* d_ws, size_t ws_size,
                              hipStream_t stream)
{
    const void* x    = d_in[0];
    const void* y    = d_in[1];
    const void* g1   = d_in[3];
    const void* b1   = d_in[4];
    const void* qkvw = d_in[5];
    const void* qkvb = d_in[6];
    const void* rpb  = d_in[7];
    const void* pw   = d_in[8];
    const void* pb   = d_in[9];
    const void* g2   = d_in[10];
    const void* b2   = d_in[11];
    const void* f1w  = d_in[12];
    const void* f1b  = d_in[13];
    const void* f2w  = d_in[14];
    const void* f2b  = d_in[15];

    char* ws = (char*)d_ws;
    const size_t OFF_Q    = 0;
    const size_t OFF_K    = 50331648;
    const size_t OFF_V    = 100663296;
    const size_t OFF_AO   = 150994944;
    const size_t OFF_X1   = 201326592;
    const size_t OFF_H    = 0;            // aliases q/k/v/ao (dead by then)
    const size_t OFF_PM   = 251658240;
    const size_t OFF_QKVT = 251674624;
    const size_t OFF_PT   = 251895808;
    const size_t OFF_F1T  = 251969536;
    const size_t OFF_F2T  = 252264448;
    const size_t OFF_FLAG = 252559360;
    const size_t WS_NEED  = 252559376;
    if (ws_size < WS_NEED) return;

    unsigned short* q    = (unsigned short*)(ws + OFF_Q);
    unsigned short* k    = (unsigned short*)(ws + OFF_K);
    unsigned short* v    = (unsigned short*)(ws + OFF_V);
    unsigned short* ao   = (unsigned short*)(ws + OFF_AO);
    unsigned short* x1   = (unsigned short*)(ws + OFF_X1);
    unsigned short* hbuf = (unsigned short*)(ws + OFF_H);
    unsigned short* pmir = (unsigned short*)(ws + OFF_PM);
    unsigned short* qkvT = (unsigned short*)(ws + OFF_QKVT);
    unsigned short* pT   = (unsigned short*)(ws + OFF_PT);
    unsigned short* f1T  = (unsigned short*)(ws + OFF_F1T);
    unsigned short* f2T  = (unsigned short*)(ws + OFF_F2T);
    int* flag            = (int*)(ws + OFF_FLAG);
    // bias table aliases the x1 region: written early, consumed by attn,
    // then proj overwrites x1 (stream-ordered, safe).
    unsigned short* biasb = (unsigned short*)(ws + OFF_X1);

    sniff_kernel<<<dim3(1), 64, 0, stream>>>((const unsigned short*)x, flag);
    convparams_kernel<<<dim3(18), 256, 0, stream>>>(g1, b1, qkvb, rpb, pb, g2, b2, f1b, f2b, flag, pmir);
    biasprep_kernel<<<dim3(96), 256, 0, stream>>>(pmir, biasb);
    wtrans_kernel<<<dim3(576, 4), 256, 0, stream>>>(qkvw, pw, f1w, f2w, qkvT, pT, f1T, f2T, flag);
    qkv_kernel<<<dim3(3, 2048), 256, 0, stream>>>(x, y, pmir, qkvT, q, k, v, flag);
    attn_kernel<<<dim3(6, 2048), 256, 0, stream>>>(q, k, v, biasb, ao);
    proj_kernel<<<dim3(2048), 256, 0, stream>>>(ao, pT, pmir, x, x1, flag);
    m1_kernel<<<dim3(4, 2048), 256, 0, stream>>>(x1, pmir, f1T, hbuf);
    m2_kernel<<<dim3(2048), 256, 0, stream>>>(hbuf, f2T, pmir, x1, d_out, flag);
}